// Round 15
// baseline (234.802 us; speedup 1.0000x reference)
//
#include <hip/hip_runtime.h>
#include <stdint.h>

// ---- problem constants ----
#define HEADS 8
#define KSZ   4
#define STRD  2
#define BB    8
#define LL    2048
#define CC    1024
#define N3    3072
#define NW    1023            // windows
#define M1    (BB*LL)         // 16384 rows of qkv GEMM (and of z GEMM)
#define GK    1024            // K of both GEMMs
#define NT2   32              // K-tiles (BK=32) per output tile

typedef __bf16 bf16;
typedef __bf16 bf16x8 __attribute__((ext_vector_type(8)));
typedef float  f32x4  __attribute__((ext_vector_type(4)));
typedef unsigned int  u32;
typedef unsigned short u16;

__device__ __forceinline__ float bflo(u32 u) { return __uint_as_float(u << 16); }
__device__ __forceinline__ float bfhi(u32 u) { return __uint_as_float(u & 0xffff0000u); }
__device__ __forceinline__ u16 f2bf(float f) { bf16 b = (bf16)f; return __builtin_bit_cast(u16, b); }

#define AS3(p) ((__attribute__((address_space(3))) void*)(p))
#define AS1(p) ((const __attribute__((address_space(1))) void*)(p))

// ---------------- merged prep: cast x + transpose both weights ----------------
__device__ __forceinline__ void tr_block(const float* __restrict__ src,
                                         bf16* __restrict__ dst,
                                         int R, int Ccol, int c0, int r0)
{
    __shared__ float t[32][33];
    int tx = threadIdx.x & 31, ty = threadIdx.x >> 5;   // 32 x 8
#pragma unroll
    for (int yy = 0; yy < 32; yy += 8)
        t[ty + yy][tx] = src[(size_t)(r0 + ty + yy) * Ccol + c0 + tx];
    __syncthreads();
#pragma unroll
    for (int yy = 0; yy < 32; yy += 8)
        dst[(size_t)(c0 + ty + yy) * R + r0 + tx] = (bf16)t[tx][ty + yy];
}

__global__ __launch_bounds__(256) void prep_k(const float* __restrict__ x,
                                              bf16* __restrict__ xb,
                                              const float* __restrict__ w_qkv,
                                              bf16* __restrict__ wqkvT,
                                              const float* __restrict__ w_out,
                                              bf16* __restrict__ woutT)
{
    int bid = blockIdx.x;
    if (bid < 2048) {
        const int n4 = M1 * CC / 4;
        int i = bid * 256 + threadIdx.x;
        for (; i < n4; i += 2048 * 256) {
            float4 f = reinterpret_cast<const float4*>(x)[i];
            ushort4 u;
            u.x = f2bf(f.x); u.y = f2bf(f.y); u.z = f2bf(f.z); u.w = f2bf(f.w);
            reinterpret_cast<ushort4*>(xb)[i] = u;
        }
    } else if (bid < 5120) {
        int t = bid - 2048;                 // 3072 blocks: 96 x 32
        tr_block(w_qkv, wqkvT, CC, N3, (t % 96) * 32, (t / 96) * 32);
    } else {
        int t = bid - 5120;                 // 1024 blocks: 32 x 32
        tr_block(w_out, woutT, CC, CC, (t & 31) * 32, (t >> 5) * 32);
    }
}

// ---------------- persistent 128x256 bf16 GEMM, BK=32, 2 blocks/CU ----------------
// Occupancy experiment: wave tile 64x64 (acc=64 AGPR), LDS 48KB doubled-buffered
// -> 2 blocks/CU (16 waves) so one block's waves fill the other's barrier stalls.
// 2-phase ledger: P1 {read a[4],b[4]; MFMA nLo; lgkm0; BAR} (all reads of
// buf[j&1] drained block-wide) ; P2 {stage A,B(j+2) into buf[j&1] (WAR-clean);
// MFMA nHi; vmcnt(3) = tile j+1 landed (3 loads/thread/K-tile); BAR}.
// BK=32 swizzle: read byte off = (l4 ^ ((l15>>1)&3))<<4 within 64B row
// (bijective over row x slot -> conflict-free); write side applies the same
// involution to the global k-chunk with linear gload_lds dest (rule 21).
__device__ __forceinline__ void stageA2(const bf16* __restrict__ G, bf16* dst,
                                        int baserow, int kt, int wid, int l)
{
    int c = wid * 64 + l;                     // chunk 0..511, row = c>>2 in [0,128)
    int row = c >> 2;
    int kc = (c & 3) ^ ((row >> 1) & 3);
    const bf16* src = G + (size_t)(baserow + row) * GK + kt * 32 + kc * 8;
    __builtin_amdgcn_global_load_lds(AS1(src), AS3(dst + wid * 512), 16, 0, 0);
}
__device__ __forceinline__ void stageB2(const bf16* __restrict__ G, bf16* dst,
                                        int baserow, int kt, int wid, int l)
{
#pragma unroll
    for (int i = 0; i < 2; ++i) {
        int c = i * 512 + wid * 64 + l;       // chunk 0..1023, row in [0,256)
        int row = c >> 2;
        int kc = (c & 3) ^ ((row >> 1) & 3);
        const bf16* src = G + (size_t)(baserow + row) * GK + kt * 32 + kc * 8;
        __builtin_amdgcn_global_load_lds(AS1(src), AS3(dst + (i * 512 + wid * 64) * 8), 16, 0, 0);
    }
}

template <int OUT_MODE, int T, int NBN>
__global__ __launch_bounds__(512, 4) void gemm2p_k(const bf16* __restrict__ A,
                                                   const bf16* __restrict__ Bt,
                                                   void* __restrict__ Cout,
                                                   const float* __restrict__ bias)
{
    __shared__ __attribute__((aligned(16))) bf16 sA[2][128 * 32];   // 2 x 8KB
    __shared__ __attribute__((aligned(16))) bf16 sB[2][256 * 32];   // 2 x 16KB
    const int Nn = NBN << 8;

    const int tid = threadIdx.x;
    const int l = tid & 63, wid = tid >> 6;
    const int wm = wid >> 2, wn = wid & 3;      // 2 x 4 wave grid, wave = 64x64
    const int l15 = l & 15, l4 = (l >> 4) & 3;
    const int offE = (l4 ^ ((l15 >> 1) & 3)) << 3;   // swizzled bf16 offset in 32-elem row

    // XCD-aware block swizzle (grid = 512, % 8 == 0, bijective)
    const int nwg = gridDim.x;
    const int wg = ((blockIdx.x & 7) * (nwg >> 3)) + (blockIdx.x >> 3);
    const int JT = T * NT2;

    int ti = wg * T;                            // current output tile
    int m0 = (ti / NBN) << 7, n0 = (ti % NBN) << 8;

    const int rA = wm * 64 + l15;
    const int rB = wn * 64 + l15;

    f32x4 acc[4][4] = {};
    bf16x8 a[4], b[4];

    // prologue: K-tile 0 -> buf0, K-tile 1 -> buf1
    stageA2(A, sA[0], m0, 0, wid, l);
    stageB2(Bt, sB[0], n0, 0, wid, l);
    stageA2(A, sA[1], m0, 1, wid, l);
    stageB2(Bt, sB[1], n0, 1, wid, l);
    asm volatile("s_waitcnt vmcnt(3)" ::: "memory");   // K-tile 0 landed
    __builtin_amdgcn_s_barrier();
    __builtin_amdgcn_sched_barrier(0);

    for (int j = 0; j < JT; ++j) {
        const bf16* tA = sA[j & 1];
        const bf16* tB = sB[j & 1];
        bf16* wA = sA[j & 1];
        bf16* wB = sB[j & 1];

        const int jn = j + 2;
        const bool doStage = jn < JT;
        int ktn = jn & (NT2 - 1), m0n = 0, n0n = 0;
        if (doStage) {
            int tin = wg * T + (jn >> 5);       // NT2 == 32
            m0n = (tin / NBN) << 7;
            n0n = (tin % NBN) << 8;
        }

        // ---- P1: read a[0..3], b[0..3]; MFMA m x nLo; lgkm0; BAR ----
#pragma unroll
        for (int f = 0; f < 4; ++f)
            a[f] = *reinterpret_cast<const bf16x8*>(&tA[(rA + f * 16) * 32 + offE]);
#pragma unroll
        for (int f = 0; f < 4; ++f)
            b[f] = *reinterpret_cast<const bf16x8*>(&tB[(rB + f * 16) * 32 + offE]);
        __builtin_amdgcn_s_setprio(1);
#pragma unroll
        for (int m = 0; m < 4; ++m)
#pragma unroll
            for (int n = 0; n < 2; ++n)
                acc[m][n] = __builtin_amdgcn_mfma_f32_16x16x32_bf16(a[m], b[n], acc[m][n], 0, 0, 0);
        __builtin_amdgcn_s_setprio(0);
        asm volatile("s_waitcnt lgkmcnt(0)" ::: "memory");   // b[2..3] drained too
        __builtin_amdgcn_sched_barrier(0);
        __builtin_amdgcn_s_barrier();
        __builtin_amdgcn_sched_barrier(0);

        // ---- P2: stage A,B(j+2) into buf[j&1]; MFMA m x nHi; vmcnt(3|0); BAR ----
        if (doStage) {
            stageA2(A, wA, m0n, ktn, wid, l);
            stageB2(Bt, wB, n0n, ktn, wid, l);
        }
        __builtin_amdgcn_s_setprio(1);
#pragma unroll
        for (int m = 0; m < 4; ++m)
#pragma unroll
            for (int n = 0; n < 2; ++n)
                acc[m][2 + n] = __builtin_amdgcn_mfma_f32_16x16x32_bf16(a[m], b[2 + n], acc[m][2 + n], 0, 0, 0);
        __builtin_amdgcn_s_setprio(0);
        if (j < JT - 2)
            asm volatile("s_waitcnt vmcnt(3)" ::: "memory");   // K-tile j+1 landed
        else if (j == JT - 2)
            asm volatile("s_waitcnt vmcnt(0)" ::: "memory");   // drain for last tile
        __builtin_amdgcn_s_barrier();
        __builtin_amdgcn_sched_barrier(0);

        // ---- output-tile boundary: epilogue (no LDS access), then reset ----
        if ((j & (NT2 - 1)) == NT2 - 1) {
            if (OUT_MODE == 0) {
                bf16* Cb = (bf16*)Cout;
#pragma unroll
                for (int mf = 0; mf < 4; ++mf) {
                    int row = m0 + wm * 64 + mf * 16 + l4 * 4;
#pragma unroll
                    for (int nf = 0; nf < 4; ++nf) {
                        int col = n0 + wn * 64 + nf * 16 + l15;
#pragma unroll
                        for (int r = 0; r < 4; ++r)
                            Cb[(size_t)(row + r) * Nn + col] = (bf16)acc[mf][nf][r];
                    }
                }
            } else {
                float* Cf = (float*)Cout;
#pragma unroll
                for (int mf = 0; mf < 4; ++mf) {
                    int row = m0 + wm * 64 + mf * 16 + l4 * 4;
#pragma unroll
                    for (int nf = 0; nf < 4; ++nf) {
                        int col = n0 + wn * 64 + nf * 16 + l15;
                        float bv = bias[col];
#pragma unroll
                        for (int r = 0; r < 4; ++r) {
                            int lrow = (row + r) & (LL - 1);
                            float cnt = (lrow < 2 || lrow > LL - 3) ? 1.f : 2.f;
                            Cf[(size_t)(row + r) * Nn + col] = acc[mf][nf][r] + bv * cnt;
                        }
                    }
                }
            }
            if (j + 1 < JT) {
#pragma unroll
                for (int mf = 0; mf < 4; ++mf)
#pragma unroll
                    for (int nf = 0; nf < 4; ++nf)
#pragma unroll
                        for (int r = 0; r < 4; ++r)
                            acc[mf][nf][r] = 0.f;
                ti += 1;
                m0 = (ti / NBN) << 7;
                n0 = (ti % NBN) << 8;
            }
        }
    }
}

// ---------------- fused attention + presum, QUAD windows: 4 waves/block ----------------
__global__ __launch_bounds__(256) void attnz4_k(const bf16* __restrict__ qkv,
                                                bf16* __restrict__ z)
{
    // XCD-chunked swizzle over 4096 blocks: contiguous (b,p) range per XCD
    int bid = (blockIdx.x & 7) * 512 + (blockIdx.x >> 3);
    int task = bid * 4 + (threadIdx.x >> 6);   // (b, p, h), h fastest
    int h = task & 7;
    int tmp = task >> 3;                       // b*256 + p
    int p = tmp & 255;
    int b = tmp >> 8;
    int l = threadIdx.x & 63;
    const int coff = h * 128 + 2 * l;          // this lane's 2 d-elements
    const int browz = b * LL + 8 * p;          // z base row (8 rows)

    float q[8][2], k[12][2], v[12][2];
#pragma unroll
    for (int i = 0; i < 8; ++i) {
        const bf16* rp = qkv + (size_t)(browz + i) * N3;
        u32 uq = *reinterpret_cast<const u32*>(rp + coff);
        q[i][0] = bflo(uq); q[i][1] = bfhi(uq);
    }
#pragma unroll
    for (int s = 0; s < 12; ++s) {
        int r = 8 * p - 2 + s;
        r = r < 0 ? 0 : (r > LL - 1 ? LL - 1 : r);    // clamp; clamped rows unused
        const bf16* rp = qkv + (size_t)(b * LL + r) * N3;
        u32 uk = *reinterpret_cast<const u32*>(rp + 1024 + coff);
        u32 uv = *reinterpret_cast<const u32*>(rp + 2048 + coff);
        k[s][0] = bflo(uk); k[s][1] = bfhi(uk);
        v[s][0] = bflo(uv); v[s][1] = bfhi(uv);
    }

    float dots[8][6];
#pragma unroll
    for (int i = 0; i < 8; ++i) {
        const int base = (i >> 1) << 1;
#pragma unroll
        for (int j = 0; j < 6; ++j) {
            float pp = q[i][0] * k[base + j][0] + q[i][1] * k[base + j][1];
#pragma unroll
            for (int off = 32; off >= 1; off >>= 1)
                pp += __shfl_xor(pp, off);
            dots[i][j] = pp * 0.03125f;   // * C^-0.5
        }
    }

#pragma unroll
    for (int i = 0; i < 8; ++i) {
        const int base = (i >> 1) << 1;
        const bool cLo = !(p == 0 && i < 2);
        const bool cHi = !(p == 255 && i >= 6);
        float o0 = 0.f, o1 = 0.f;
        if (cLo) {    // window n1-1: slots base..base+3
            float m = fmaxf(fmaxf(dots[i][0], dots[i][1]), fmaxf(dots[i][2], dots[i][3]));
            float e[4], s = 0.f;
#pragma unroll
            for (int j = 0; j < 4; ++j) { e[j] = __expf(dots[i][j] - m); s += e[j]; }
            float inv = 1.f / s;
#pragma unroll
            for (int j = 0; j < 4; ++j) {
                float aa = e[j] * inv;
                o0 += aa * v[base + j][0];
                o1 += aa * v[base + j][1];
            }
        }
        if (cHi) {    // window n1: slots base+2..base+5
            float m = fmaxf(fmaxf(dots[i][2], dots[i][3]), fmaxf(dots[i][4], dots[i][5]));
            float e[4], s = 0.f;
#pragma unroll
            for (int j = 0; j < 4; ++j) { e[j] = __expf(dots[i][2 + j] - m); s += e[j]; }
            float inv = 1.f / s;
#pragma unroll
            for (int j = 0; j < 4; ++j) {
                float aa = e[j] * inv;
                o0 += aa * v[base + 2 + j][0];
                o1 += aa * v[base + 2 + j][1];
            }
        }
        u32 pk = (u32)f2bf(o0) | ((u32)f2bf(o1) << 16);
        *reinterpret_cast<u32*>(z + (size_t)(browz + i) * CC + coff) = pk;
    }
}

// ---------------- launch ----------------
extern "C" void kernel_launch(void* const* d_in, const int* in_sizes, int n_in,
                              void* d_out, int out_size, void* d_ws, size_t ws_size,
                              hipStream_t stream)
{
    const float* x     = (const float*)d_in[0];
    const float* w_qkv = (const float*)d_in[1];
    const float* w_out = (const float*)d_in[2];
    const float* b_out = (const float*)d_in[3];
    float* out = (float*)d_out;
    char* ws = (char*)d_ws;

    // ws layout (bytes):
    bf16* xb    = (bf16*)(ws);                  // 16384*1024*2  = 33,554,432
    bf16* wqkvT = (bf16*)(ws + 33554432);       //  3072*1024*2  =  6,291,456
    bf16* woutT = (bf16*)(ws + 39845888);       //  1024*1024*2  =  2,097,152
    bf16* qkvb  = (bf16*)(ws + 41943040);       // 16384*3072*2  = 100,663,296 (ends 142,606,336)
    bf16* z     = (bf16*)(ws + 142606336);      // 16384*1024*2  = 33,554,432
    // total: 176,160,768 bytes

    // merged prep: cast x + transpose w_qkv + transpose w_out
    prep_k<<<6144, 256, 0, stream>>>(x, xb, w_qkv, wqkvT, w_out, woutT);

    // GEMM1: 16384x3072x1024 -> 128x12 = 1536 tiles -> 512 blocks x 3 tiles
    gemm2p_k<0, 3, 12><<<512, 512, 0, stream>>>(xb, wqkvT, qkvb, nullptr);

    // fused attention + presum (quad windows): 8*256*8 = 16384 waves, 4/block
    attnz4_k<<<4096, 256, 0, stream>>>(qkvb, z);

    // GEMM2: 16384x1024x1024 -> 128x4 = 512 tiles -> 512 blocks x 1 tile, f32 out + bias*cnt
    gemm2p_k<1, 1, 4><<<512, 512, 0, stream>>>(z, woutT, out, b_out);
}

// Round 16
// 209.789 us; speedup vs baseline: 1.1192x; 1.1192x over previous
//
#include <hip/hip_runtime.h>
#include <stdint.h>

// ---- problem constants ----
#define HEADS 8
#define KSZ   4
#define STRD  2
#define BB    8
#define LL    2048
#define CC    1024
#define N3    3072
#define NW    1023            // windows
#define M1    (BB*LL)         // 16384 rows of qkv GEMM (and of z GEMM)
#define GK    1024            // K of both GEMMs
#define NTT   16              // K-tiles per output tile (GK/64)

typedef __bf16 bf16;
typedef __bf16 bf16x8 __attribute__((ext_vector_type(8)));
typedef float  f32x4  __attribute__((ext_vector_type(4)));
typedef unsigned int  u32;
typedef unsigned short u16;

__device__ __forceinline__ float bflo(u32 u) { return __uint_as_float(u << 16); }
__device__ __forceinline__ float bfhi(u32 u) { return __uint_as_float(u & 0xffff0000u); }
__device__ __forceinline__ u16 f2bf(float f) { bf16 b = (bf16)f; return __builtin_bit_cast(u16, b); }

#define AS3(p) ((__attribute__((address_space(3))) void*)(p))
#define AS1(p) ((const __attribute__((address_space(1))) void*)(p))

// ---------------- merged prep: cast x + transpose both weights ----------------
__device__ __forceinline__ void tr_block(const float* __restrict__ src,
                                         bf16* __restrict__ dst,
                                         int R, int Ccol, int c0, int r0)
{
    __shared__ float t[32][33];
    int tx = threadIdx.x & 31, ty = threadIdx.x >> 5;   // 32 x 8
#pragma unroll
    for (int yy = 0; yy < 32; yy += 8)
        t[ty + yy][tx] = src[(size_t)(r0 + ty + yy) * Ccol + c0 + tx];
    __syncthreads();
#pragma unroll
    for (int yy = 0; yy < 32; yy += 8)
        dst[(size_t)(c0 + ty + yy) * R + r0 + tx] = (bf16)t[tx][ty + yy];
}

__global__ __launch_bounds__(256) void prep_k(const float* __restrict__ x,
                                              bf16* __restrict__ xb,
                                              const float* __restrict__ w_qkv,
                                              bf16* __restrict__ wqkvT,
                                              const float* __restrict__ w_out,
                                              bf16* __restrict__ woutT)
{
    int bid = blockIdx.x;
    if (bid < 2048) {
        const int n4 = M1 * CC / 4;
        int i = bid * 256 + threadIdx.x;
        for (; i < n4; i += 2048 * 256) {
            float4 f = reinterpret_cast<const float4*>(x)[i];
            ushort4 u;
            u.x = f2bf(f.x); u.y = f2bf(f.y); u.z = f2bf(f.z); u.w = f2bf(f.w);
            reinterpret_cast<ushort4*>(xb)[i] = u;
        }
    } else if (bid < 5120) {
        int t = bid - 2048;                 // 3072 blocks: 96 x 32
        tr_block(w_qkv, wqkvT, CC, N3, (t % 96) * 32, (t / 96) * 32);
    } else {
        int t = bid - 5120;                 // 1024 blocks: 32 x 32
        tr_block(w_out, woutT, CC, CC, (t & 31) * 32, (t >> 5) * 32);
    }
}

// ---------------- persistent 256x256 8-phase bf16 GEMM (r8 verified body, FROZEN) ----------------
// Rolled j-loop, reads after leading barrier, stage A(j+2)@P3, B(j+2)@P4 into
// buf[j&1]; vmcnt(8)@P4 steady, vmcnt(0)@JT-2. NBN template (magic-mul div).
// OUT_MODE 0 = bf16 C, 1 = f32 C direct to d_out with bias[col]*cnt(row).
// 953 TF verified; 7 structural variants (r6,r9,r10,r11,r13,r15) all lost to it.
__device__ __forceinline__ void stage8(const bf16* __restrict__ G, bf16* dst,
                                       int baserow, int kt,
                                       int wid, int l, int kch)
{
#pragma unroll
    for (int qd = 0; qd < 4; ++qd) {
        int row = ((wid * 4 + qd) << 3) + (l >> 3);
        const bf16* src = G + (size_t)(baserow + row) * GK + kt * 64 + kch;
        __builtin_amdgcn_global_load_lds(AS1(src), AS3(dst + (wid * 4 + qd) * 512), 16, 0, 0);
    }
}

template <int OUT_MODE, int T, int NBN>
__global__ __launch_bounds__(512, 1) void gemm8p_k(const bf16* __restrict__ A,
                                                   const bf16* __restrict__ Bt,
                                                   void* __restrict__ Cout,
                                                   const float* __restrict__ bias)
{
    __shared__ __attribute__((aligned(16))) bf16 sA[2][256 * 64];
    __shared__ __attribute__((aligned(16))) bf16 sB[2][256 * 64];
    const int Nn = NBN << 8;

    const int tid = threadIdx.x;
    const int l = tid & 63, wid = tid >> 6;
    const int wm = wid >> 2, wn = wid & 3;
    const int l15 = l & 15, l4 = l >> 4;
    const int xr = (l & 7) << 4;                      // read-side byte XOR (row&7 == l&7)
    const int kch = ((l & 7) ^ ((l >> 3) & 7)) * 8;   // write-side inverse-swizzled k offset

    // XCD-aware block swizzle (grid = 256, % 8 == 0, bijective)
    const int nwg = gridDim.x;
    const int wg = ((blockIdx.x & 7) * (nwg >> 3)) + (blockIdx.x >> 3);
    const int JT = T * NTT;

    int ti = wg * T;                                  // current output tile
    int m0 = (ti / NBN) << 8, n0 = (ti % NBN) << 8;

    const int rA = wm * 128 + l15;
    const int rB = wn * 64 + l15;
    int offK[2];
#pragma unroll
    for (int ks = 0; ks < 2; ++ks)
        offK[ks] = ((ks * 64 + l4 * 16) ^ xr) >> 1;

    f32x4 acc[8][4] = {};
    bf16x8 aLo[4][2], aHi[4][2], bLo[2][2], bHi[2][2];

    // prologue: K-tile 0 -> buf0, K-tile 1 -> buf1 (tile ti)
    stage8(A, sA[0], m0, 0, wid, l, kch);
    stage8(Bt, sB[0], n0, 0, wid, l, kch);
    stage8(A, sA[1], m0, 1, wid, l, kch);
    stage8(Bt, sB[1], n0, 1, wid, l, kch);
    asm volatile("s_waitcnt vmcnt(8)" ::: "memory");   // K-tile 0 landed
    __builtin_amdgcn_s_barrier();
    __builtin_amdgcn_sched_barrier(0);

    for (int j = 0; j < JT; ++j) {
        const bf16* tA = sA[j & 1];
        const bf16* tB = sB[j & 1];
        bf16* wA = sA[j & 1];
        bf16* wB = sB[j & 1];

        // next-stage coordinates (tile of j+2)
        const int jn = j + 2;
        const bool doStage = jn < JT;
        int ktn = jn & (NTT - 1), m0n = 0, n0n = 0;
        if (doStage) {
            int tin = wg * T + (jn >> 4);              // NTT == 16
            m0n = (tin / NBN) << 8;
            n0n = (tin % NBN) << 8;
        }

        // ---- P1: ds aLo(8) + bLo(4); MFMA m0-3 x n0-1 ----
#pragma unroll
        for (int m = 0; m < 4; ++m)
#pragma unroll
            for (int ks = 0; ks < 2; ++ks)
                aLo[m][ks] = *reinterpret_cast<const bf16x8*>(&tA[(rA + m * 16) * 64 + offK[ks]]);
#pragma unroll
        for (int n = 0; n < 2; ++n)
#pragma unroll
            for (int ks = 0; ks < 2; ++ks)
                bLo[n][ks] = *reinterpret_cast<const bf16x8*>(&tB[(rB + n * 16) * 64 + offK[ks]]);
        __builtin_amdgcn_s_setprio(1);
#pragma unroll
        for (int m = 0; m < 4; ++m)
#pragma unroll
            for (int n = 0; n < 2; ++n)
#pragma unroll
                for (int ks = 0; ks < 2; ++ks)
                    acc[m][n] = __builtin_amdgcn_mfma_f32_16x16x32_bf16(aLo[m][ks], bLo[n][ks], acc[m][n], 0, 0, 0);
        __builtin_amdgcn_s_setprio(0);
        __builtin_amdgcn_s_barrier();
        __builtin_amdgcn_sched_barrier(0);

        // ---- P2: ds aHi(8); MFMA m4-7 x n0-1 ----  (A region fully read after this)
#pragma unroll
        for (int m = 0; m < 4; ++m)
#pragma unroll
            for (int ks = 0; ks < 2; ++ks)
                aHi[m][ks] = *reinterpret_cast<const bf16x8*>(&tA[(rA + 64 + m * 16) * 64 + offK[ks]]);
        __builtin_amdgcn_s_setprio(1);
#pragma unroll
        for (int m = 0; m < 4; ++m)
#pragma unroll
            for (int n = 0; n < 2; ++n)
#pragma unroll
                for (int ks = 0; ks < 2; ++ks)
                    acc[4 + m][n] = __builtin_amdgcn_mfma_f32_16x16x32_bf16(aHi[m][ks], bLo[n][ks], acc[4 + m][n], 0, 0, 0);
        __builtin_amdgcn_s_setprio(0);
        __builtin_amdgcn_s_barrier();
        __builtin_amdgcn_sched_barrier(0);

        // ---- P3: ds bHi(4); stage A(j+2) into freed A region; MFMA m4-7 x n2-3 ----
#pragma unroll
        for (int n = 0; n < 2; ++n)
#pragma unroll
            for (int ks = 0; ks < 2; ++ks)
                bHi[n][ks] = *reinterpret_cast<const bf16x8*>(&tB[(rB + 32 + n * 16) * 64 + offK[ks]]);
        if (doStage)
            stage8(A, wA, m0n, ktn, wid, l, kch);
        __builtin_amdgcn_s_setprio(1);
#pragma unroll
        for (int m = 0; m < 4; ++m)
#pragma unroll
            for (int n = 0; n < 2; ++n)
#pragma unroll
                for (int ks = 0; ks < 2; ++ks)
                    acc[4 + m][2 + n] = __builtin_amdgcn_mfma_f32_16x16x32_bf16(aHi[m][ks], bHi[n][ks], acc[4 + m][2 + n], 0, 0, 0);
        __builtin_amdgcn_s_setprio(0);
        __builtin_amdgcn_s_barrier();
        __builtin_amdgcn_sched_barrier(0);

        // ---- P4: stage B(j+2) into freed B region; MFMA m0-3 x n2-3; counted vmcnt ----
        if (doStage)
            stage8(Bt, wB, n0n, ktn, wid, l, kch);
        __builtin_amdgcn_s_setprio(1);
#pragma unroll
        for (int m = 0; m < 4; ++m)
#pragma unroll
            for (int n = 0; n < 2; ++n)
#pragma unroll
                for (int ks = 0; ks < 2; ++ks)
                    acc[m][2 + n] = __builtin_amdgcn_mfma_f32_16x16x32_bf16(aLo[m][ks], bHi[n][ks], acc[m][2 + n], 0, 0, 0);
        __builtin_amdgcn_s_setprio(0);
        if (j < JT - 2)
            asm volatile("s_waitcnt vmcnt(8)" ::: "memory");   // K-tile j+1 landed
        else if (j == JT - 2)
            asm volatile("s_waitcnt vmcnt(0)" ::: "memory");   // drain for last tile
        __builtin_amdgcn_s_barrier();
        __builtin_amdgcn_sched_barrier(0);

        // ---- output-tile boundary: epilogue (no LDS access), then reset ----
        if ((j & (NTT - 1)) == NTT - 1) {
            if (OUT_MODE == 0) {
                bf16* Cb = (bf16*)Cout;
#pragma unroll
                for (int m = 0; m < 8; ++m) {
                    int row = m0 + wm * 128 + m * 16 + l4 * 4;
#pragma unroll
                    for (int n = 0; n < 4; ++n) {
                        int col = n0 + wn * 64 + n * 16 + l15;
#pragma unroll
                        for (int r = 0; r < 4; ++r)
                            Cb[(size_t)(row + r) * Nn + col] = (bf16)acc[m][n][r];
                    }
                }
            } else {
                float* Cf = (float*)Cout;
#pragma unroll
                for (int m = 0; m < 8; ++m) {
                    int row = m0 + wm * 128 + m * 16 + l4 * 4;
#pragma unroll
                    for (int n = 0; n < 4; ++n) {
                        int col = n0 + wn * 64 + n * 16 + l15;
                        float bv = bias[col];
#pragma unroll
                        for (int r = 0; r < 4; ++r) {
                            int lrow = (row + r) & (LL - 1);
                            float cnt = (lrow < 2 || lrow > LL - 3) ? 1.f : 2.f;
                            Cf[(size_t)(row + r) * Nn + col] = acc[m][n][r] + bv * cnt;
                        }
                    }
                }
            }
            if (j + 1 < JT) {
#pragma unroll
                for (int m = 0; m < 8; ++m)
#pragma unroll
                    for (int n = 0; n < 4; ++n)
#pragma unroll
                        for (int r = 0; r < 4; ++r)
                            acc[m][n][r] = 0.f;
                ti += 1;
                m0 = (ti / NBN) << 8;
                n0 = (ti % NBN) << 8;
            }
        }
    }
}

// ---------------- fused attention + presum, pair windows, 2 heads/wave ----------------
// One wave per (b, p, hp): lanes 0-31 = head 2*hp, lanes 32-63 = head 2*hp+1;
// each lane holds 4 consecutive d-elems (uint2 = 8B loads, G13 sweet spot).
// Pair geometry (r12-verified): p in [0,512), z rows 4p..4p+3; K/V slots
// s=0..7 <-> rows 4p-2+s. Row i: base=(i<2)?0:2; Lo window slots base..base+3
// (absent iff p==0 && i<2); Hi window slots base+2..base+5 (absent iff p==511
// && i>=2). Reductions: 5-level shfl_xor (16..1) stays within each 32-half.
__global__ __launch_bounds__(256) void attnz2w_k(const bf16* __restrict__ qkv,
                                                 bf16* __restrict__ z)
{
    // XCD-chunked swizzle over 4096 blocks: contiguous (b,p) range per XCD
    int bid = (blockIdx.x & 7) * 512 + (blockIdx.x >> 3);
    int task = bid * 4 + (threadIdx.x >> 6);   // (b, p, hp), hp fastest
    int hp = task & 3;
    int tmp = task >> 2;                       // b*512 + p
    int p = tmp & 511;
    int b = tmp >> 9;
    int l = threadIdx.x & 63;
    const int coff = hp * 256 + 4 * l;         // 4 d-elems; lanes>=32 -> head 2hp+1
    const int browz = b * LL + 4 * p;          // z base row (4 rows)

    float q[4][4], k[8][4], v[8][4];
#pragma unroll
    for (int i = 0; i < 4; ++i) {
        uint2 u = *reinterpret_cast<const uint2*>(qkv + (size_t)(browz + i) * N3 + coff);
        q[i][0] = bflo(u.x); q[i][1] = bfhi(u.x);
        q[i][2] = bflo(u.y); q[i][3] = bfhi(u.y);
    }
#pragma unroll
    for (int s = 0; s < 8; ++s) {
        int r = 4 * p - 2 + s;
        r = r < 0 ? 0 : (r > LL - 1 ? LL - 1 : r);    // clamp; clamped rows unused
        const bf16* rp = qkv + (size_t)(b * LL + r) * N3 + coff;
        uint2 uk = *reinterpret_cast<const uint2*>(rp + 1024);
        uint2 uv = *reinterpret_cast<const uint2*>(rp + 2048);
        k[s][0] = bflo(uk.x); k[s][1] = bfhi(uk.x);
        k[s][2] = bflo(uk.y); k[s][3] = bfhi(uk.y);
        v[s][0] = bflo(uv.x); v[s][1] = bfhi(uv.x);
        v[s][2] = bflo(uv.y); v[s][3] = bfhi(uv.y);
    }

    // dots[i][j] = q_i . k[base_i + j] over this half's 128 dims
    float dots[4][6];
#pragma unroll
    for (int i = 0; i < 4; ++i) {
        const int base = (i < 2) ? 0 : 2;
#pragma unroll
        for (int j = 0; j < 6; ++j) {
            float pp = q[i][0] * k[base + j][0] + q[i][1] * k[base + j][1]
                     + q[i][2] * k[base + j][2] + q[i][3] * k[base + j][3];
#pragma unroll
            for (int off = 16; off >= 1; off >>= 1)
                pp += __shfl_xor(pp, off);
            dots[i][j] = pp * 0.03125f;   // * C^-0.5
        }
    }

#pragma unroll
    for (int i = 0; i < 4; ++i) {
        const int base = (i < 2) ? 0 : 2;
        const bool cLo = (i < 2) ? (p > 0) : true;
        const bool cHi = (i < 2) ? true : (p < 511);
        float o0 = 0.f, o1 = 0.f, o2 = 0.f, o3 = 0.f;
        if (cLo) {    // window over j 0..3 (v slots base..base+3)
            float m = fmaxf(fmaxf(dots[i][0], dots[i][1]), fmaxf(dots[i][2], dots[i][3]));
            float e[4], s = 0.f;
#pragma unroll
            for (int j = 0; j < 4; ++j) { e[j] = __expf(dots[i][j] - m); s += e[j]; }
            float inv = 1.f / s;
#pragma unroll
            for (int j = 0; j < 4; ++j) {
                float a = e[j] * inv;
                o0 += a * v[base + j][0];
                o1 += a * v[base + j][1];
                o2 += a * v[base + j][2];
                o3 += a * v[base + j][3];
            }
        }
        if (cHi) {    // window over j 2..5 (v slots base+2..base+5)
            float m = fmaxf(fmaxf(dots[i][2], dots[i][3]), fmaxf(dots[i][4], dots[i][5]));
            float e[4], s = 0.f;
#pragma unroll
            for (int j = 0; j < 4; ++j) { e[j] = __expf(dots[i][2 + j] - m); s += e[j]; }
            float inv = 1.f / s;
#pragma unroll
            for (int j = 0; j < 4; ++j) {
                float a = e[j] * inv;
                o0 += a * v[base + 2 + j][0];
                o1 += a * v[base + 2 + j][1];
                o2 += a * v[base + 2 + j][2];
                o3 += a * v[base + 2 + j][3];
            }
        }
        uint2 pk;
        pk.x = (u32)f2bf(o0) | ((u32)f2bf(o1) << 16);
        pk.y = (u32)f2bf(o2) | ((u32)f2bf(o3) << 16);
        *reinterpret_cast<uint2*>(z + (size_t)(browz + i) * CC + coff) = pk;
    }
}

// ---------------- launch ----------------
extern "C" void kernel_launch(void* const* d_in, const int* in_sizes, int n_in,
                              void* d_out, int out_size, void* d_ws, size_t ws_size,
                              hipStream_t stream)
{
    const float* x     = (const float*)d_in[0];
    const float* w_qkv = (const float*)d_in[1];
    const float* w_out = (const float*)d_in[2];
    const float* b_out = (const float*)d_in[3];
    float* out = (float*)d_out;
    char* ws = (char*)d_ws;

    // ws layout (bytes):
    bf16* xb    = (bf16*)(ws);                  // 16384*1024*2  = 33,554,432
    bf16* wqkvT = (bf16*)(ws + 33554432);       //  3072*1024*2  =  6,291,456
    bf16* woutT = (bf16*)(ws + 39845888);       //  1024*1024*2  =  2,097,152
    bf16* qkvb  = (bf16*)(ws + 41943040);       // 16384*3072*2  = 100,663,296 (ends 142,606,336)
    bf16* z     = (bf16*)(ws + 142606336);      // 16384*1024*2  = 33,554,432
    // total: 176,160,768 bytes

    // merged prep: cast x + transpose w_qkv + transpose w_out
    prep_k<<<6144, 256, 0, stream>>>(x, xb, w_qkv, wqkvT, w_out, woutT);

    // GEMM1: 16384x3072x1024 = 768 tiles -> 256 persistent blocks x 3 tiles
    gemm8p_k<0, 3, 12><<<256, 512, 0, stream>>>(xb, wqkvT, qkvb, nullptr);

    // fused attention + presum (pair windows, 2 heads/wave): 8*512*4 = 16384 waves
    attnz2w_k<<<4096, 256, 0, stream>>>(qkvb, z);

    // GEMM2: 16384x1024x1024 = 256 tiles -> 256 blocks x 1 tile, f32 out + bias*cnt
    gemm8p_k<1, 1, 4><<<256, 512, 0, stream>>>(z, woutT, out, b_out);
}